// Round 26
// baseline (200.645 us; speedup 1.0000x reference)
//
#include <hip/hip_runtime.h>
#include <cstdint>
#include <cstddef>

#define S_LEN   2048
#define N_HEADS 8
#define N_BATCH 2
#define TOPK    409      // int(2048 * (1.0 - 0.8)) in python double arithmetic
#define HALF_WIN 32
#define KEY_P0  0x80000000u   // mono(+0.0f)
#define KEY_N0  0x7FFFFFFFu   // mono(-0.0f)  (total order: -0 < +0)
#define HIST_STRIDE 260       // words; wave w's hist row starts at bank 4w
#define NWAVE   2             // waves per block
#define HPW     4             // heads per wave

__device__ __forceinline__ unsigned mbcnt64(unsigned long long m) {
  return __builtin_amdgcn_mbcnt_hi((unsigned)(m >> 32),
         __builtin_amdgcn_mbcnt_lo((unsigned)m, 0u));
}

__device__ __forceinline__ unsigned mono1(float f) {
  unsigned u = __float_as_uint(f);
  return (u & 0x80000000u) ? ~u : (u | 0x80000000u);
}

// MSD radix select over the positive (key>+0) or negative (key<-0) subset.
// Wave-scope (no barriers). Keys in a register array.
__device__ __forceinline__ void radix_range(const unsigned (&keys)[32], unsigned kk0,
                                            bool pos, unsigned* h, int l,
                                            unsigned& T_ret, unsigned& kk_ret,
                                            bool& cnt1) {
  unsigned prefix = 0, done = 0, kk = kk0;
  unsigned T = 0;
  bool resolved = false;
  cnt1 = false;
  #pragma unroll
  for (int pass = 0; pass < 4; ++pass) {
    const int shift = 24 - 8 * pass;
    *(uint4*)&h[l * 4] = make_uint4(0, 0, 0, 0);
    __threadfence_block();
    #pragma unroll
    for (int q = 0; q < 32; ++q) {
      unsigned kj = keys[q];
      bool in = pos ? (kj > KEY_P0) : (kj < KEY_N0);
      if (in && (kj & done) == prefix)
        atomicAdd(&h[(kj >> shift) & 255u], 1u);
    }
    __threadfence_block();
    uint4 hv = *(const uint4*)&h[l * 4];
    unsigned s3 = hv.w;
    unsigned s2 = hv.z + s3;
    unsigned s1 = hv.y + s2;
    unsigned s0 = hv.x + s1;
    unsigned inc = s0;
    #pragma unroll
    for (int d = 1; d < 64; d <<= 1) {
      unsigned o = __shfl_down(inc, d);
      inc += (l + d < 64) ? o : 0u;
    }
    const unsigned tail = inc - s0;
    const unsigned ge[4] = {s0 + tail, s1 + tail, s2 + tail, s3 + tail};
    const unsigned gt[4] = {s1 + tail, s2 + tail, s3 + tail, tail};
    unsigned packed = 0;
    bool found = false;
    #pragma unroll
    for (int q = 0; q < 4; ++q) {
      if (gt[q] < kk && kk <= ge[q]) {
        packed = ((unsigned)(4 * l + q) << 24) | ((ge[q] - gt[q]) << 12) | (kk - gt[q]);
        found = true;
      }
    }
    unsigned long long bal = __ballot(found);
    int srcl = __ffsll((long long)bal) - 1;
    packed = __shfl(packed, srcl);
    const unsigned cnt = (packed >> 12) & 0xFFFu;
    kk = packed & 0xFFFu;
    prefix |= (packed >> 24) << shift;
    done |= 0xFFu << shift;
    if (cnt == 1u) {
      unsigned cand = 0;
      #pragma unroll
      for (int q = 0; q < 32; ++q) {
        unsigned kj = keys[q];
        bool in = pos ? (kj > KEY_P0) : (kj < KEY_N0);
        if (in && (kj & done) == prefix) cand = kj;
      }
      #pragma unroll
      for (int d = 1; d < 64; d <<= 1) cand |= __shfl_xor(cand, d);
      T = cand;                              // kk == 1 here
      resolved = true;
      cnt1 = true;
      break;
    }
  }
  if (!resolved) T = prefix;
  T_ret = T;
  kk_ret = kk;
}

// Resolve threshold T + tie-take count kk for top-TOPK of 2048 keys (32/lane).
// Order: positives > +0 > -0 > negatives; n0/n1 counted lazily.
__device__ __forceinline__ void resolve_T(const unsigned (&keys)[32], unsigned* h,
                                          int l, unsigned& T, unsigned& kk,
                                          bool& cnt1) {
  unsigned np = 0;
  #pragma unroll
  for (int q = 0; q < 32; ++q)
    np += (unsigned)__popcll(__ballot(keys[q] > KEY_P0));
  if (TOPK <= np) {
    radix_range(keys, TOPK, true, h, l, T, kk, cnt1);
  } else {
    unsigned n0 = 0, n1 = 0;
    #pragma unroll
    for (int q = 0; q < 32; ++q) {
      unsigned kj = keys[q];
      n0 += (unsigned)__popcll(__ballot(kj == KEY_P0));
      n1 += (unsigned)__popcll(__ballot(kj == KEY_N0));
    }
    if (TOPK <= np + n0)           { T = KEY_P0; kk = TOPK - np;      cnt1 = (n0 == 1); }
    else if (TOPK <= np + n0 + n1) { T = KEY_N0; kk = TOPK - np - n0; cnt1 = (n1 == 1); }
    else radix_range(keys, TOPK - np - n0 - n1, false, h, l, T, kk, cnt1);
  }
}

// Per-lane selection bits (bit q=4s+e <-> column j=256s+4l+e). Stable
// lowest-index-first tie handling; ballot-free fast path when cnt1.
__device__ __forceinline__ unsigned select_bits(const unsigned (&keys)[32],
                                                unsigned T, unsigned kk,
                                                bool cnt1, int l) {
  unsigned bits = 0;
  if (cnt1) {
    #pragma unroll
    for (int q = 0; q < 32; ++q)
      bits |= (keys[q] >= T ? 1u : 0u) << q;
    return bits;
  }
  unsigned S_tot = 0;
  #pragma unroll
  for (int s = 0; s < 8; ++s) {
    unsigned long long beq[4];
    unsigned pe[4];
    #pragma unroll
    for (int e = 0; e < 4; ++e) {
      beq[e] = __ballot(keys[4 * s + e] == T);
      pe[e] = (unsigned)__popcll(beq[e]);
    }
    const unsigned th = pe[0] + pe[1] + pe[2] + pe[3];
    if (S_tot + th <= kk) {
      #pragma unroll
      for (int e = 0; e < 4; ++e)
        bits |= (keys[4 * s + e] >= T ? 1u : 0u) << (4 * s + e);
    } else if (S_tot >= kk) {
      #pragma unroll
      for (int e = 0; e < 4; ++e)
        bits |= (keys[4 * s + e] > T ? 1u : 0u) << (4 * s + e);
    } else {                                 // boundary block (exactly one)
      unsigned mb[4], own[4];
      #pragma unroll
      for (int e = 0; e < 4; ++e) {
        mb[e]  = mbcnt64(beq[e]);
        own[e] = (unsigned)((beq[e] >> l) & 1ull);
      }
      const unsigned cross = S_tot + mb[0] + mb[1] + mb[2] + mb[3];
      unsigned run = 0;
      #pragma unroll
      for (int e = 0; e < 4; ++e) {
        unsigned kj = keys[4 * s + e];
        bool sel = (kj > T) || (kj == T && (cross + run) < kk);
        run += own[e];
        bits |= (sel ? 1u : 0u) << (4 * s + e);
      }
    }
    S_tot += th;
  }
  return bits;
}

// Fused kernel: block = (b,i), 128 threads = 2 waves, 4 heads per wave.
// Hypothesis: per-CU workgroup-slot cap (~16) limited 256-thr blocks to
// 16 waves/CU (50%); at 128-thr, 15-16 blocks x 2 waves = 30-32 waves/CU
// (HW max 8/SIMD) -> double the latency-hiding TLP. Structure is R23
// verbatim otherwise: divergent wave-0 gmask select (publishes gq) while
// wave 1 preloads its head-A; JIT loads for remaining heads (score rows
// L2-warm from P2, rand cold); transposed keyrow (stride-1 reload);
// spill-safe single-array live sets (compiler pins ~44-64 VGPR).
__global__ __launch_bounds__(128, 4) void k_fused(const float* __restrict__ scores,
                                                  const float* __restrict__ randu,
                                                  float* __restrict__ out) {
  __shared__ __align__(16) unsigned keyrow[S_LEN];             // 8 KB
  __shared__ __align__(16) unsigned hist[NWAVE * HIST_STRIDE]; // 2.1 KB
  __shared__ unsigned gq[64];                                  // select words
  const int l = threadIdx.x & 63;          // lane
  const int w = threadIdx.x >> 6;          // wave 0..1
  const int bi = blockIdx.x;               // b * S + i
  const int b = bi >> 11;
  const int i = bi & 2047;
  const size_t gbase = (((size_t)(b * N_HEADS)) * S_LEN + i) * S_LEN; // head 0
  const float thr = (float)(1.0 - 0.8);    // 0x3E4CCCCD, JAX f32 demotion
  unsigned* const h = hist + (size_t)w * HIST_STRIDE;
  const size_t rowA = gbase + (size_t)(HPW * w) * S_LEN * S_LEN;

  // ---- P2: head-sum of own 1024-col slice (four 256-col chunks) ----
  #pragma unroll
  for (int t = 0; t < HPW; ++t) {
    const int s = HPW * w + t;             // 256-col chunk index
    const int c0 = 256 * s + 4 * l;
    float4 p = *(const float4*)(scores + gbase + c0);
    #pragma unroll
    for (int hh = 1; hh < N_HEADS; ++hh) {  // sequential head order
      float4 x = *(const float4*)(scores + gbase + (size_t)hh * S_LEN * S_LEN + c0);
      p.x += x.x; p.y += x.y; p.z += x.z; p.w += x.w;
    }
    const float av[4] = {p.x, p.y, p.z, p.w};
    #pragma unroll
    for (int e = 0; e < 4; ++e)
      keyrow[(4 * s + e) * 64 + l] = mono1(av[e]);   // column 256s+4l+e
  }
  __syncthreads();

  // ---- Divergent: wave 0 gmask-selects; wave 1 preloads its head A ----
  unsigned sbA[32];
  unsigned rndA = 0;
  if (w == 0) {
    unsigned gk[32];
    #pragma unroll
    for (int q = 0; q < 32; ++q)
      gk[q] = keyrow[q * 64 + l];            // stride-1: conflict-free
    unsigned Tg, kkg; bool c1g;
    resolve_T(gk, hist, l, Tg, kkg, c1g);
    unsigned gbits = select_bits(gk, Tg, kkg, c1g, l);
    const int lo = i - HALF_WIN;             // window [i-32, i+32)
    #pragma unroll
    for (int q = 0; q < 32; ++q) {
      const int j = 256 * (q >> 2) + 4 * l + (q & 3);
      gbits |= ((unsigned)(j - lo) < 64u ? 1u : 0u) << q;
    }
    gq[l] = gbits;
  } else {
    #pragma unroll
    for (int s = 0; s < 8; ++s) {
      const int j0 = 256 * s + 4 * l;
      float4 sc = *(const float4*)(scores + rowA + j0);  // L2-warm (P2)
      float4 ru = *(const float4*)(randu + rowA + j0);   // cold (HBM)
      sbA[4 * s + 0] = __float_as_uint(sc.x);
      sbA[4 * s + 1] = __float_as_uint(sc.y);
      sbA[4 * s + 2] = __float_as_uint(sc.z);
      sbA[4 * s + 3] = __float_as_uint(sc.w);
      rndA |= (ru.x < thr ? 1u : 0u) << (4 * s + 0);
      rndA |= (ru.y < thr ? 1u : 0u) << (4 * s + 1);
      rndA |= (ru.z < thr ? 1u : 0u) << (4 * s + 2);
      rndA |= (ru.w < thr ? 1u : 0u) << (4 * s + 3);
    }
  }
  __syncthreads();
  const unsigned gql = gq[l];

  // ---- P3b head A: wave 0 loads JIT; wave 1 has operands in regs ----
  if (w == 0) {
    #pragma unroll
    for (int s = 0; s < 8; ++s) {
      const int j0 = 256 * s + 4 * l;
      float4 sc = *(const float4*)(scores + rowA + j0);
      float4 ru = *(const float4*)(randu + rowA + j0);
      sbA[4 * s + 0] = __float_as_uint(sc.x);
      sbA[4 * s + 1] = __float_as_uint(sc.y);
      sbA[4 * s + 2] = __float_as_uint(sc.z);
      sbA[4 * s + 3] = __float_as_uint(sc.w);
      rndA |= (ru.x < thr ? 1u : 0u) << (4 * s + 0);
      rndA |= (ru.y < thr ? 1u : 0u) << (4 * s + 1);
      rndA |= (ru.z < thr ? 1u : 0u) << (4 * s + 2);
      rndA |= (ru.w < thr ? 1u : 0u) << (4 * s + 3);
    }
  }
  {
    const unsigned combined = gql | rndA;
    #pragma unroll
    for (int q = 0; q < 32; ++q) {
      const unsigned u = sbA[q];
      const unsigned m = (unsigned)((int)u >> 31) | 0x80000000u;
      const bool comb = ((combined >> q) & 1u) != 0u;
      sbA[q] = (comb ? u : (u & 0x80000000u)) ^ m;
    }
    unsigned T, kk; bool c1;
    resolve_T(sbA, h, l, T, kk, c1);
    unsigned bits = select_bits(sbA, T, kk, c1, l);
    #pragma unroll
    for (int s = 0; s < 8; ++s) {
      float v[4] __attribute__((aligned(16)));
      #pragma unroll
      for (int e = 0; e < 4; ++e)
        v[e] = ((bits >> (4 * s + e)) & 1u) ? 1.0f : 0.0f;
      *(float4*)(out + rowA + 256 * s + 4 * l) = *(const float4*)v;
    }
  }

  // ---- P3b heads 1..3 of this wave: JIT loads, select, write ----
  #pragma unroll 1
  for (int t = 1; t < HPW; ++t) {
    const size_t rowh = rowA + (size_t)t * S_LEN * S_LEN;
    unsigned sb[32];
    unsigned rnd = 0;
    #pragma unroll
    for (int s = 0; s < 8; ++s) {
      const int j0 = 256 * s + 4 * l;
      float4 sc = *(const float4*)(scores + rowh + j0);  // L2-warm (P2)
      float4 ru = *(const float4*)(randu + rowh + j0);   // cold (only read)
      sb[4 * s + 0] = __float_as_uint(sc.x);
      sb[4 * s + 1] = __float_as_uint(sc.y);
      sb[4 * s + 2] = __float_as_uint(sc.z);
      sb[4 * s + 3] = __float_as_uint(sc.w);
      rnd |= (ru.x < thr ? 1u : 0u) << (4 * s + 0);
      rnd |= (ru.y < thr ? 1u : 0u) << (4 * s + 1);
      rnd |= (ru.z < thr ? 1u : 0u) << (4 * s + 2);
      rnd |= (ru.w < thr ? 1u : 0u) << (4 * s + 3);
    }
    const unsigned combined = gql | rnd;
    #pragma unroll
    for (int q = 0; q < 32; ++q) {
      const unsigned u = sb[q];
      const unsigned m = (unsigned)((int)u >> 31) | 0x80000000u;
      const bool comb = ((combined >> q) & 1u) != 0u;
      sb[q] = (comb ? u : (u & 0x80000000u)) ^ m;
    }
    unsigned T, kk; bool c1;
    resolve_T(sb, h, l, T, kk, c1);
    unsigned bits = select_bits(sb, T, kk, c1, l);
    #pragma unroll
    for (int s = 0; s < 8; ++s) {
      float v[4] __attribute__((aligned(16)));
      #pragma unroll
      for (int e = 0; e < 4; ++e)
        v[e] = ((bits >> (4 * s + e)) & 1u) ? 1.0f : 0.0f;
      *(float4*)(out + rowh + 256 * s + 4 * l) = *(const float4*)v;
    }
  }
}

extern "C" void kernel_launch(void* const* d_in, const int* in_sizes, int n_in,
                              void* d_out, int out_size, void* d_ws, size_t ws_size,
                              hipStream_t stream) {
  const float* scores = (const float*)d_in[0];
  const float* randu  = (const float*)d_in[1];
  float* out = (float*)d_out;
  (void)d_ws; (void)ws_size;
  k_fused<<<N_BATCH * S_LEN, NWAVE * 64, 0, stream>>>(scores, randu, out);
}

// Round 27
// 186.904 us; speedup vs baseline: 1.0735x; 1.0735x over previous
//
#include <hip/hip_runtime.h>
#include <cstdint>
#include <cstddef>

#define S_LEN   2048
#define N_HEADS 8
#define N_BATCH 2
#define TOPK    409      // int(2048 * (1.0 - 0.8)) in python double arithmetic
#define HALF_WIN 32
#define KEY_P0  0x80000000u   // mono(+0.0f)
#define KEY_N0  0x7FFFFFFFu   // mono(-0.0f)  (total order: -0 < +0)
#define HIST_STRIDE 260       // words; wave w's hist row starts at bank 4w

__device__ __forceinline__ unsigned mbcnt64(unsigned long long m) {
  return __builtin_amdgcn_mbcnt_hi((unsigned)(m >> 32),
         __builtin_amdgcn_mbcnt_lo((unsigned)m, 0u));
}

__device__ __forceinline__ unsigned mono1(float f) {
  unsigned u = __float_as_uint(f);
  return (u & 0x80000000u) ? ~u : (u | 0x80000000u);
}

// MSD radix select over the positive (key>+0) or negative (key<-0) subset.
// Wave-scope (no barriers). Keys in a register array.
__device__ __forceinline__ void radix_range(const unsigned (&keys)[32], unsigned kk0,
                                            bool pos, unsigned* h, int l,
                                            unsigned& T_ret, unsigned& kk_ret,
                                            bool& cnt1) {
  unsigned prefix = 0, done = 0, kk = kk0;
  unsigned T = 0;
  bool resolved = false;
  cnt1 = false;
  #pragma unroll
  for (int pass = 0; pass < 4; ++pass) {
    const int shift = 24 - 8 * pass;
    *(uint4*)&h[l * 4] = make_uint4(0, 0, 0, 0);
    __threadfence_block();
    #pragma unroll
    for (int q = 0; q < 32; ++q) {
      unsigned kj = keys[q];
      bool in = pos ? (kj > KEY_P0) : (kj < KEY_N0);
      if (in && (kj & done) == prefix)
        atomicAdd(&h[(kj >> shift) & 255u], 1u);
    }
    __threadfence_block();
    uint4 hv = *(const uint4*)&h[l * 4];
    unsigned s3 = hv.w;
    unsigned s2 = hv.z + s3;
    unsigned s1 = hv.y + s2;
    unsigned s0 = hv.x + s1;
    unsigned inc = s0;
    #pragma unroll
    for (int d = 1; d < 64; d <<= 1) {
      unsigned o = __shfl_down(inc, d);
      inc += (l + d < 64) ? o : 0u;
    }
    const unsigned tail = inc - s0;
    const unsigned ge[4] = {s0 + tail, s1 + tail, s2 + tail, s3 + tail};
    const unsigned gt[4] = {s1 + tail, s2 + tail, s3 + tail, tail};
    unsigned packed = 0;
    bool found = false;
    #pragma unroll
    for (int q = 0; q < 4; ++q) {
      if (gt[q] < kk && kk <= ge[q]) {
        packed = ((unsigned)(4 * l + q) << 24) | ((ge[q] - gt[q]) << 12) | (kk - gt[q]);
        found = true;
      }
    }
    unsigned long long bal = __ballot(found);
    int srcl = __ffsll((long long)bal) - 1;
    packed = __shfl(packed, srcl);
    const unsigned cnt = (packed >> 12) & 0xFFFu;
    kk = packed & 0xFFFu;
    prefix |= (packed >> 24) << shift;
    done |= 0xFFu << shift;
    if (cnt == 1u) {
      unsigned cand = 0;
      #pragma unroll
      for (int q = 0; q < 32; ++q) {
        unsigned kj = keys[q];
        bool in = pos ? (kj > KEY_P0) : (kj < KEY_N0);
        if (in && (kj & done) == prefix) cand = kj;
      }
      #pragma unroll
      for (int d = 1; d < 64; d <<= 1) cand |= __shfl_xor(cand, d);
      T = cand;                              // kk == 1 here
      resolved = true;
      cnt1 = true;
      break;
    }
  }
  if (!resolved) T = prefix;
  T_ret = T;
  kk_ret = kk;
}

// Resolve threshold T + tie-take count kk for top-TOPK of 2048 keys (32/lane).
// Order: positives > +0 > -0 > negatives; n0/n1 counted lazily.
__device__ __forceinline__ void resolve_T(const unsigned (&keys)[32], unsigned* h,
                                          int l, unsigned& T, unsigned& kk,
                                          bool& cnt1) {
  unsigned np = 0;
  #pragma unroll
  for (int q = 0; q < 32; ++q)
    np += (unsigned)__popcll(__ballot(keys[q] > KEY_P0));
  if (TOPK <= np) {
    radix_range(keys, TOPK, true, h, l, T, kk, cnt1);
  } else {
    unsigned n0 = 0, n1 = 0;
    #pragma unroll
    for (int q = 0; q < 32; ++q) {
      unsigned kj = keys[q];
      n0 += (unsigned)__popcll(__ballot(kj == KEY_P0));
      n1 += (unsigned)__popcll(__ballot(kj == KEY_N0));
    }
    if (TOPK <= np + n0)           { T = KEY_P0; kk = TOPK - np;      cnt1 = (n0 == 1); }
    else if (TOPK <= np + n0 + n1) { T = KEY_N0; kk = TOPK - np - n0; cnt1 = (n1 == 1); }
    else radix_range(keys, TOPK - np - n0 - n1, false, h, l, T, kk, cnt1);
  }
}

// Per-lane selection bits (bit q=4s+e <-> column j=256s+4l+e). Stable
// lowest-index-first tie handling; ballot-free fast path when cnt1.
__device__ __forceinline__ unsigned select_bits(const unsigned (&keys)[32],
                                                unsigned T, unsigned kk,
                                                bool cnt1, int l) {
  unsigned bits = 0;
  if (cnt1) {
    #pragma unroll
    for (int q = 0; q < 32; ++q)
      bits |= (keys[q] >= T ? 1u : 0u) << q;
    return bits;
  }
  unsigned S_tot = 0;
  #pragma unroll
  for (int s = 0; s < 8; ++s) {
    unsigned long long beq[4];
    unsigned pe[4];
    #pragma unroll
    for (int e = 0; e < 4; ++e) {
      beq[e] = __ballot(keys[4 * s + e] == T);
      pe[e] = (unsigned)__popcll(beq[e]);
    }
    const unsigned th = pe[0] + pe[1] + pe[2] + pe[3];
    if (S_tot + th <= kk) {
      #pragma unroll
      for (int e = 0; e < 4; ++e)
        bits |= (keys[4 * s + e] >= T ? 1u : 0u) << (4 * s + e);
    } else if (S_tot >= kk) {
      #pragma unroll
      for (int e = 0; e < 4; ++e)
        bits |= (keys[4 * s + e] > T ? 1u : 0u) << (4 * s + e);
    } else {                                 // boundary block (exactly one)
      unsigned mb[4], own[4];
      #pragma unroll
      for (int e = 0; e < 4; ++e) {
        mb[e]  = mbcnt64(beq[e]);
        own[e] = (unsigned)((beq[e] >> l) & 1ull);
      }
      const unsigned cross = S_tot + mb[0] + mb[1] + mb[2] + mb[3];
      unsigned run = 0;
      #pragma unroll
      for (int e = 0; e < 4; ++e) {
        unsigned kj = keys[4 * s + e];
        bool sel = (kj > T) || (kj == T && (cross + run) < kk);
        run += own[e];
        bits |= (sel ? 1u : 0u) << (4 * s + e);
      }
    }
    S_tot += th;
  }
  return bits;
}

// Fused kernel: block = (b,i), 256 threads = 4 waves, 2 heads per wave.
// = R23, the session's best (184.3us, reproduced 189.3us): after keyrow is
// ready, wave 0 runs the gmask select (publishes gq) while waves 1-3 preload
// their head-A score/rand rows. Spill-safe: no program point holds BOTH
// gk[32] and sbA[32] -- wave 0 skips the preload and loads head A JIT after
// the barrier. Head B stays JIT for all waves. Compiler pins this kernel at
// ~44-64 VGPRs; each path's peak live set is one 32-word array + temps.
// Bracketing variants all slower: 64-thr 1-wave barrier-free (R24, +16%),
// 128-thr 2-wave (R26, +9%), 512-thr (R14/R17, +10%), any extra prefetch
// (R20/R21, spill), redundant select (R22, neutral), extra staging barriers
// (R16, +35%). Achieved occupancy pins at ~40-50% regardless of block size
// -- scheduler-level cap, not configurable from source.
__global__ __launch_bounds__(256, 4) void k_fused(const float* __restrict__ scores,
                                                  const float* __restrict__ randu,
                                                  float* __restrict__ out) {
  __shared__ __align__(16) unsigned keyrow[S_LEN];         // 8 KB gmask keys
  __shared__ __align__(16) unsigned hist[4 * HIST_STRIDE]; // 4.2 KB
  __shared__ unsigned gq[64];                              // select words
  const int l = threadIdx.x & 63;          // lane
  const int w = threadIdx.x >> 6;          // wave 0..3
  const int bi = blockIdx.x;               // b * S + i
  const int b = bi >> 11;
  const int i = bi & 2047;
  const size_t gbase = (((size_t)(b * N_HEADS)) * S_LEN + i) * S_LEN; // head 0
  const float thr = (float)(1.0 - 0.8);    // 0x3E4CCCCD, JAX f32 demotion
  unsigned* const h = hist + (size_t)w * HIST_STRIDE;
  const size_t rowA = gbase + (size_t)(2 * w) * S_LEN * S_LEN;
  const size_t rowB = rowA + (size_t)S_LEN * S_LEN;

  // ---- P2: head-sum of own 512-col slice (two 256-col chunks) ----
  #pragma unroll
  for (int t = 0; t < 2; ++t) {
    const int s = 2 * w + t;               // 256-col chunk index
    const int c0 = 256 * s + 4 * l;
    float4 p = *(const float4*)(scores + gbase + c0);
    #pragma unroll
    for (int hh = 1; hh < N_HEADS; ++hh) {  // sequential head order
      float4 x = *(const float4*)(scores + gbase + (size_t)hh * S_LEN * S_LEN + c0);
      p.x += x.x; p.y += x.y; p.z += x.z; p.w += x.w;
    }
    const float av[4] = {p.x, p.y, p.z, p.w};
    #pragma unroll
    for (int e = 0; e < 4; ++e)
      keyrow[(4 * s + e) * 64 + l] = mono1(av[e]);   // column 256s+4l+e
  }
  __syncthreads();

  // ---- Divergent: wave 0 gmask-selects; waves 1-3 preload head A ----
  unsigned sbA[32];
  unsigned rndA = 0;
  if (w == 0) {
    unsigned gk[32];
    #pragma unroll
    for (int q = 0; q < 32; ++q)
      gk[q] = keyrow[q * 64 + l];            // stride-1: conflict-free
    unsigned Tg, kkg; bool c1g;
    resolve_T(gk, hist, l, Tg, kkg, c1g);
    unsigned gbits = select_bits(gk, Tg, kkg, c1g, l);
    const int lo = i - HALF_WIN;             // window [i-32, i+32)
    #pragma unroll
    for (int q = 0; q < 32; ++q) {
      const int j = 256 * (q >> 2) + 4 * l + (q & 3);
      gbits |= ((unsigned)(j - lo) < 64u ? 1u : 0u) << q;
    }
    gq[l] = gbits;
  } else {
    #pragma unroll
    for (int s = 0; s < 8; ++s) {
      const int j0 = 256 * s + 4 * l;
      float4 sc = *(const float4*)(scores + rowA + j0);  // L2-warm (P2)
      float4 ru = *(const float4*)(randu + rowA + j0);   // cold (HBM)
      sbA[4 * s + 0] = __float_as_uint(sc.x);
      sbA[4 * s + 1] = __float_as_uint(sc.y);
      sbA[4 * s + 2] = __float_as_uint(sc.z);
      sbA[4 * s + 3] = __float_as_uint(sc.w);
      rndA |= (ru.x < thr ? 1u : 0u) << (4 * s + 0);
      rndA |= (ru.y < thr ? 1u : 0u) << (4 * s + 1);
      rndA |= (ru.z < thr ? 1u : 0u) << (4 * s + 2);
      rndA |= (ru.w < thr ? 1u : 0u) << (4 * s + 3);
    }
  }
  __syncthreads();
  const unsigned gql = gq[l];

  // ---- P3b head A: wave 0 loads JIT; others have operands in regs ----
  if (w == 0) {
    #pragma unroll
    for (int s = 0; s < 8; ++s) {
      const int j0 = 256 * s + 4 * l;
      float4 sc = *(const float4*)(scores + rowA + j0);
      float4 ru = *(const float4*)(randu + rowA + j0);
      sbA[4 * s + 0] = __float_as_uint(sc.x);
      sbA[4 * s + 1] = __float_as_uint(sc.y);
      sbA[4 * s + 2] = __float_as_uint(sc.z);
      sbA[4 * s + 3] = __float_as_uint(sc.w);
      rndA |= (ru.x < thr ? 1u : 0u) << (4 * s + 0);
      rndA |= (ru.y < thr ? 1u : 0u) << (4 * s + 1);
      rndA |= (ru.z < thr ? 1u : 0u) << (4 * s + 2);
      rndA |= (ru.w < thr ? 1u : 0u) << (4 * s + 3);
    }
  }
  {
    const unsigned combined = gql | rndA;
    #pragma unroll
    for (int q = 0; q < 32; ++q) {
      const unsigned u = sbA[q];
      const unsigned m = (unsigned)((int)u >> 31) | 0x80000000u;
      const bool comb = ((combined >> q) & 1u) != 0u;
      sbA[q] = (comb ? u : (u & 0x80000000u)) ^ m;
    }
    unsigned T, kk; bool c1;
    resolve_T(sbA, h, l, T, kk, c1);
    unsigned bits = select_bits(sbA, T, kk, c1, l);
    #pragma unroll
    for (int s = 0; s < 8; ++s) {
      float v[4] __attribute__((aligned(16)));
      #pragma unroll
      for (int e = 0; e < 4; ++e)
        v[e] = ((bits >> (4 * s + e)) & 1u) ? 1.0f : 0.0f;
      *(float4*)(out + rowA + 256 * s + 4 * l) = *(const float4*)v;
    }
  }

  // ---- P3b head B: JIT loads (score L2-warm, rand cold), select, write ----
  {
    unsigned sbB[32];
    unsigned rndB = 0;
    #pragma unroll
    for (int s = 0; s < 8; ++s) {
      const int j0 = 256 * s + 4 * l;
      float4 sc = *(const float4*)(scores + rowB + j0);
      float4 ru = *(const float4*)(randu + rowB + j0);
      sbB[4 * s + 0] = __float_as_uint(sc.x);
      sbB[4 * s + 1] = __float_as_uint(sc.y);
      sbB[4 * s + 2] = __float_as_uint(sc.z);
      sbB[4 * s + 3] = __float_as_uint(sc.w);
      rndB |= (ru.x < thr ? 1u : 0u) << (4 * s + 0);
      rndB |= (ru.y < thr ? 1u : 0u) << (4 * s + 1);
      rndB |= (ru.z < thr ? 1u : 0u) << (4 * s + 2);
      rndB |= (ru.w < thr ? 1u : 0u) << (4 * s + 3);
    }
    const unsigned combined = gql | rndB;
    #pragma unroll
    for (int q = 0; q < 32; ++q) {
      const unsigned u = sbB[q];
      const unsigned m = (unsigned)((int)u >> 31) | 0x80000000u;
      const bool comb = ((combined >> q) & 1u) != 0u;
      sbB[q] = (comb ? u : (u & 0x80000000u)) ^ m;
    }
    unsigned T, kk; bool c1;
    resolve_T(sbB, h, l, T, kk, c1);
    unsigned bits = select_bits(sbB, T, kk, c1, l);
    #pragma unroll
    for (int s = 0; s < 8; ++s) {
      float v[4] __attribute__((aligned(16)));
      #pragma unroll
      for (int e = 0; e < 4; ++e)
        v[e] = ((bits >> (4 * s + e)) & 1u) ? 1.0f : 0.0f;
      *(float4*)(out + rowB + 256 * s + 4 * l) = *(const float4*)v;
    }
  }
}

extern "C" void kernel_launch(void* const* d_in, const int* in_sizes, int n_in,
                              void* d_out, int out_size, void* d_ws, size_t ws_size,
                              hipStream_t stream) {
  const float* scores = (const float*)d_in[0];
  const float* randu  = (const float*)d_in[1];
  float* out = (float*)d_out;
  (void)d_ws; (void)ws_size;
  k_fused<<<N_BATCH * S_LEN, 256, 0, stream>>>(scores, randu, out);
}